// Round 1
// baseline (419.093 us; speedup 1.0000x reference)
//
#include <hip/hip_runtime.h>

typedef unsigned short u16;
typedef unsigned int u32;

#define SPA 2744        // 14*14*14 tokens
#define CH  768
#define NH  12
#define DH  64
#define BB  2
#define TC  2304        // 3*CH
#define MTOT (BB*SPA)   // 5488

typedef __bf16 bf16x8_t __attribute__((ext_vector_type(8)));
typedef float  f32x4_t  __attribute__((ext_vector_type(4)));

static __device__ __forceinline__ u16 f2bf(float f) {
    union { float f; u32 u; } v; v.f = f;
    u32 u = v.u;
    u += 0x7fffu + ((u >> 16) & 1u);   // RNE
    return (u16)(u >> 16);
}
static __device__ __forceinline__ float bf2f(u16 h) {
    union { u32 u; float f; } v; v.u = ((u32)h) << 16;
    return v.f;
}

// ---------------- fp32 -> bf16 weight conversion ----------------
__global__ __launch_bounds__(256) void cvt_bf16_kernel(const float* __restrict__ in,
                                                       u16* __restrict__ out, int n4) {
    int i = blockIdx.x * 256 + threadIdx.x;
    if (i < n4) {
        float4 f = ((const float4*)in)[i];
        uint2 o;
        o.x = (u32)f2bf(f.x) | ((u32)f2bf(f.y) << 16);
        o.y = (u32)f2bf(f.z) | ((u32)f2bf(f.w) << 16);
        ((uint2*)out)[i] = o;
    }
}

// ---------------- LayerNorm over channels, write token-major bf16 ----------------
__global__ __launch_bounds__(256) void ln_kernel(const float* __restrict__ x,
                                                 const float* __restrict__ w,
                                                 const float* __restrict__ bta,
                                                 u16* __restrict__ tn) {
    int tok = blockIdx.x;            // b*SPA + n
    int b = tok / SPA, n = tok - b * SPA;
    int tid = threadIdx.x;
    const float* xb = x + (size_t)b * CH * SPA + n;
    float v0 = xb[(size_t)tid * SPA];
    float v1 = xb[(size_t)(tid + 256) * SPA];
    float v2 = xb[(size_t)(tid + 512) * SPA];
    float s = v0 + v1 + v2;
    float q = v0 * v0 + v1 * v1 + v2 * v2;
    for (int off = 32; off; off >>= 1) { s += __shfl_xor(s, off); q += __shfl_xor(q, off); }
    __shared__ float red[8];
    int wv = tid >> 6;
    if ((tid & 63) == 0) { red[wv] = s; red[4 + wv] = q; }
    __syncthreads();
    s = red[0] + red[1] + red[2] + red[3];
    q = red[4] + red[5] + red[6] + red[7];
    float mean = s * (1.0f / CH);
    float var = q * (1.0f / CH) - mean * mean;
    float rstd = rsqrtf(var + 1e-5f);
    u16* o = tn + (size_t)tok * CH;
    o[tid]       = f2bf((v0 - mean) * rstd * w[tid]       + bta[tid]);
    o[tid + 256] = f2bf((v1 - mean) * rstd * w[tid + 256] + bta[tid + 256]);
    o[tid + 512] = f2bf((v2 - mean) * rstd * w[tid + 512] + bta[tid + 512]);
}

// ---------------- bf16 GEMM, C[m][n] = sum_k A[m][k]*Bw[n][k] ----------------
// MODE 0: scatter epilogue -> q/k/v [b][h][n][d].  MODE 1: plain bf16 [M][CH].
template<int MODE>
__global__ __launch_bounds__(256, 2) void gemm_bt(const u16* __restrict__ A,
                                                  const u16* __restrict__ Bw,
                                                  u16* __restrict__ out0,
                                                  u16* __restrict__ out1,
                                                  u16* __restrict__ out2,
                                                  int M, int K) {
    __shared__ __align__(16) u16 As[128 * 40];
    __shared__ __align__(16) u16 Bs[128 * 40];
    int tid = threadIdx.x;
    int m0 = blockIdx.y * 128;
    int n0 = blockIdx.x * 128;
    int wv = tid >> 6, lane = tid & 63;
    int wm = (wv >> 1) * 64, wn = (wv & 1) * 64;
    int quad = lane >> 4, l16 = lane & 15;

    f32x4_t zero = {0.f, 0.f, 0.f, 0.f};
    f32x4_t acc[4][4];
#pragma unroll
    for (int i = 0; i < 4; i++)
#pragma unroll
        for (int j = 0; j < 4; j++) acc[i][j] = zero;

    int arow0 = tid >> 2, acs = tid & 3;
    for (int k0 = 0; k0 < K; k0 += 32) {
        __syncthreads();
#pragma unroll
        for (int h = 0; h < 2; h++) {
            int row = arow0 + h * 64;
            int gm = m0 + row;
            int4 aval = make_int4(0, 0, 0, 0);
            if (gm < M) aval = *(const int4*)(A + (size_t)gm * K + k0 + acs * 8);
            *(int4*)(As + row * 40 + acs * 8) = aval;
            int4 bval = *(const int4*)(Bw + (size_t)(n0 + row) * K + k0 + acs * 8);
            *(int4*)(Bs + row * 40 + acs * 8) = bval;
        }
        __syncthreads();
        bf16x8_t af[4], bfr[4];
#pragma unroll
        for (int i = 0; i < 4; i++) af[i] = *(const bf16x8_t*)(As + (wm + i * 16 + l16) * 40 + quad * 8);
#pragma unroll
        for (int j = 0; j < 4; j++) bfr[j] = *(const bf16x8_t*)(Bs + (wn + j * 16 + l16) * 40 + quad * 8);
#pragma unroll
        for (int i = 0; i < 4; i++)
#pragma unroll
            for (int j = 0; j < 4; j++)
                acc[i][j] = __builtin_amdgcn_mfma_f32_16x16x32_bf16(af[i], bfr[j], acc[i][j], 0, 0, 0);
    }

    if (MODE == 0) {
        int which = n0 / CH;                  // block-uniform (CH % 128 == 0)
        int rb = n0 - which * CH;
        u16* base = (which == 0) ? out0 : ((which == 1) ? out1 : out2);
#pragma unroll
        for (int i = 0; i < 4; i++)
#pragma unroll
            for (int r = 0; r < 4; r++) {
                int gm = m0 + wm + i * 16 + quad * 4 + r;
                if (gm < M) {
                    int b = gm / SPA, n = gm - b * SPA;
#pragma unroll
                    for (int j = 0; j < 4; j++) {
                        int rem = rb + wn + j * 16 + l16;
                        int h = rem >> 6, d = rem & 63;
                        base[((size_t)(b * NH + h) * SPA + n) * DH + d] = f2bf(acc[i][j][r]);
                    }
                }
            }
    } else {
#pragma unroll
        for (int i = 0; i < 4; i++)
#pragma unroll
            for (int r = 0; r < 4; r++) {
                int gm = m0 + wm + i * 16 + quad * 4 + r;
                if (gm < M) {
#pragma unroll
                    for (int j = 0; j < 4; j++) {
                        int gn = n0 + wn + j * 16 + l16;
                        out0[(size_t)gm * CH + gn] = f2bf(acc[i][j][r]);
                    }
                }
            }
    }
}

// ---------------- V transpose: [bh][n][d] -> [bh][d][n] ----------------
__global__ __launch_bounds__(256) void vtrans_kernel(const u16* __restrict__ v,
                                                     u16* __restrict__ vt) {
    __shared__ __align__(16) u16 T[64 * 72];
    int bh = blockIdx.y;
    int n0 = blockIdx.x * 64;
    int tid = threadIdx.x;
#pragma unroll
    for (int h = 0; h < 2; h++) {
        int chunk = tid + h * 256;
        int r = chunk >> 3, cs = chunk & 7;
        int n = n0 + r;
        int4 val = make_int4(0, 0, 0, 0);
        if (n < SPA) val = *(const int4*)(v + ((size_t)bh * SPA + n) * DH + cs * 8);
        *(int4*)(T + r * 72 + cs * 8) = val;
    }
    __syncthreads();
#pragma unroll
    for (int h = 0; h < 2; h++) {
        int chunk = tid + h * 256;
        int d = chunk >> 3, cs = chunk & 7;
        int nb = n0 + cs * 8;
        if (nb < SPA) {                       // SPA % 8 == 0 -> chunk fully valid
            union { u16 s[8]; int4 v4; } tmp;
#pragma unroll
            for (int e = 0; e < 8; e++) tmp.s[e] = T[(cs * 8 + e) * 72 + d];
            *(int4*)(vt + ((size_t)bh * DH + d) * SPA + nb) = tmp.v4;
        }
    }
}

// ---------------- flash attention: block = (qtile, h, b), 4 waves x 16 q-rows ----------------
__global__ __launch_bounds__(256, 2) void attn_kernel(const u16* __restrict__ q,
                                                      const u16* __restrict__ k,
                                                      const u16* __restrict__ vt,
                                                      u16* __restrict__ out) {
    __shared__ __align__(16) u16 Qs[64 * 72];
    __shared__ __align__(16) u16 Ks[64 * 72];
    __shared__ __align__(16) u16 Vs[64 * 72];
    __shared__ __align__(16) u16 Ps[4][16 * 72];
    int qt = blockIdx.x, h = blockIdx.y, b = blockIdx.z;
    int bh = b * NH + h;
    int tid = threadIdx.x;
    int wv = tid >> 6, lane = tid & 63;
    int quad = lane >> 4, l16 = lane & 15;
    int q0 = qt * 64;

    const u16* qg = q + (size_t)bh * SPA * DH;
    const u16* kg = k + (size_t)bh * SPA * DH;
    const u16* vg = vt + (size_t)bh * DH * SPA;

#pragma unroll
    for (int t2 = 0; t2 < 2; t2++) {
        int chunk = tid + t2 * 256;
        int r = chunk >> 3, cs = chunk & 7;
        int n = q0 + r;
        int4 val = make_int4(0, 0, 0, 0);
        if (n < SPA) val = *(const int4*)(qg + (size_t)n * DH + cs * 8);
        *(int4*)(Qs + r * 72 + cs * 8) = val;
    }

    f32x4_t zero = {0.f, 0.f, 0.f, 0.f};
    f32x4_t o[4];
#pragma unroll
    for (int i = 0; i < 4; i++) o[i] = zero;
    float mrow[4], lrow[4];
#pragma unroll
    for (int r = 0; r < 4; r++) { mrow[r] = -1e30f; lrow[r] = 0.f; }

    const int nkv = (SPA + 63) / 64;
    for (int kt = 0; kt < nkv; kt++) {
        int kv0 = kt * 64;
        __syncthreads();
#pragma unroll
        for (int t2 = 0; t2 < 2; t2++) {
            int chunk = tid + t2 * 256;
            int r = chunk >> 3, cs = chunk & 7;
            int n = kv0 + r;
            int4 kval = make_int4(0, 0, 0, 0);
            if (n < SPA) kval = *(const int4*)(kg + (size_t)n * DH + cs * 8);
            *(int4*)(Ks + r * 72 + cs * 8) = kval;
            int4 vval = make_int4(0, 0, 0, 0);
            int nb = kv0 + cs * 8;
            if (nb < SPA) vval = *(const int4*)(vg + (size_t)r * SPA + nb);
            *(int4*)(Vs + r * 72 + cs * 8) = vval;
        }
        __syncthreads();

        // S = Q*K^T  (16 q-rows per wave x 64 kv-cols)
        f32x4_t s[4];
#pragma unroll
        for (int j = 0; j < 4; j++) s[j] = zero;
#pragma unroll
        for (int ks = 0; ks < 2; ks++) {
            bf16x8_t aq = *(const bf16x8_t*)(Qs + (wv * 16 + l16) * 72 + ks * 32 + quad * 8);
#pragma unroll
            for (int j = 0; j < 4; j++) {
                bf16x8_t bk = *(const bf16x8_t*)(Ks + (j * 16 + l16) * 72 + ks * 32 + quad * 8);
                s[j] = __builtin_amdgcn_mfma_f32_16x16x32_bf16(aq, bk, s[j], 0, 0, 0);
            }
        }
        // scale + mask invalid kv columns
        const float sc = 0.125f;   // dh^-0.5
#pragma unroll
        for (int j = 0; j < 4; j++) {
            bool valid = (kv0 + j * 16 + l16) < SPA;
#pragma unroll
            for (int r = 0; r < 4; r++)
                s[j][r] = valid ? s[j][r] * sc : -1e30f;
        }
        // row max over 64 cols (4 local + 16-lane butterfly)
        float mnew[4], alpha[4];
#pragma unroll
        for (int r = 0; r < 4; r++) {
            float m = fmaxf(fmaxf(s[0][r], s[1][r]), fmaxf(s[2][r], s[3][r]));
#pragma unroll
            for (int msk = 1; msk < 16; msk <<= 1) m = fmaxf(m, __shfl_xor(m, msk));
            mnew[r] = fmaxf(mrow[r], m);
            alpha[r] = __expf(mrow[r] - mnew[r]);
            mrow[r] = mnew[r];
        }
        float tsum[4] = {0.f, 0.f, 0.f, 0.f};
#pragma unroll
        for (int j = 0; j < 4; j++)
#pragma unroll
            for (int r = 0; r < 4; r++) {
                float p = __expf(s[j][r] - mnew[r]);
                s[j][r] = p;
                tsum[r] += p;
            }
#pragma unroll
        for (int r = 0; r < 4; r++) {
            float t = tsum[r];
#pragma unroll
            for (int msk = 1; msk < 16; msk <<= 1) t += __shfl_xor(t, msk);
            lrow[r] = lrow[r] * alpha[r] + t;
        }
#pragma unroll
        for (int i = 0; i < 4; i++)
#pragma unroll
            for (int r = 0; r < 4; r++) o[i][r] *= alpha[r];

        // P (C-layout) -> LDS -> A-operand layout (per-wave buffer, same-wave in-order DS)
        u16* pw = &Ps[wv][0];
#pragma unroll
        for (int j = 0; j < 4; j++)
#pragma unroll
            for (int r = 0; r < 4; r++)
                pw[(quad * 4 + r) * 72 + j * 16 + l16] = f2bf(s[j][r]);

#pragma unroll
        for (int ks = 0; ks < 2; ks++) {
            bf16x8_t ap = *(const bf16x8_t*)(pw + l16 * 72 + ks * 32 + quad * 8);
#pragma unroll
            for (int i = 0; i < 4; i++) {
                bf16x8_t bv = *(const bf16x8_t*)(Vs + (i * 16 + l16) * 72 + ks * 32 + quad * 8);
                o[i] = __builtin_amdgcn_mfma_f32_16x16x32_bf16(ap, bv, o[i], 0, 0, 0);
            }
        }
    }

#pragma unroll
    for (int r = 0; r < 4; r++) {
        int n = q0 + wv * 16 + quad * 4 + r;
        if (n < SPA) {
            float inv = 1.0f / lrow[r];
#pragma unroll
            for (int i = 0; i < 4; i++)
                out[((size_t)(b * SPA + n)) * CH + h * DH + i * 16 + l16] = f2bf(o[i][r] * inv);
        }
    }
}

// ---------------- final: transpose back + bias + residual ----------------
__global__ __launch_bounds__(256) void final_kernel(const u16* __restrict__ proj,
                                                    const float* __restrict__ ob,
                                                    const float* __restrict__ x,
                                                    float* __restrict__ out) {
    int idx = blockIdx.x * 256 + threadIdx.x;   // 0 .. BB*CH*(SPA/4)-1
    int s4 = idx % (SPA / 4);
    int t = idx / (SPA / 4);
    int c = t % CH;
    int b = t / CH;
    int n = s4 * 4;
    size_t xoff = ((size_t)(b * CH + c)) * SPA + n;
    float4 xv = *(const float4*)(x + xoff);
    const u16* pp = proj + ((size_t)(b * SPA + n)) * CH + c;
    float bias = ob[c];
    float4 r;
    r.x = xv.x + bias + bf2f(pp[0]);
    r.y = xv.y + bias + bf2f(pp[CH]);
    r.z = xv.z + bias + bf2f(pp[2 * CH]);
    r.w = xv.w + bias + bf2f(pp[3 * CH]);
    *(float4*)(out + xoff) = r;
}

extern "C" void kernel_launch(void* const* d_in, const int* in_sizes, int n_in,
                              void* d_out, int out_size, void* d_ws, size_t ws_size,
                              hipStream_t stream) {
    const float* x      = (const float*)d_in[0];
    const float* norm_w = (const float*)d_in[1];
    const float* norm_b = (const float*)d_in[2];
    const float* qkv_w  = (const float*)d_in[3];
    const float* out_w  = (const float*)d_in[4];
    const float* out_b  = (const float*)d_in[5];
    float* out = (float*)d_out;

    char* ws = (char*)d_ws;
    size_t off = 0;
    auto alloc = [&](size_t bytes) -> void* {
        void* p = ws + off;
        off += (bytes + 255) & ~(size_t)255;
        return p;
    };
    u16* tn      = (u16*)alloc((size_t)MTOT * CH * 2);
    u16* qkvw_bf = (u16*)alloc((size_t)TC * CH * 2);
    u16* outw_bf = (u16*)alloc((size_t)CH * CH * 2);
    u16* qb      = (u16*)alloc((size_t)BB * NH * SPA * DH * 2);
    u16* kb      = (u16*)alloc((size_t)BB * NH * SPA * DH * 2);
    u16* vb      = (u16*)alloc((size_t)BB * NH * SPA * DH * 2);
    u16* vtb     = (u16*)alloc((size_t)BB * NH * SPA * DH * 2);
    u16* ao      = (u16*)alloc((size_t)MTOT * CH * 2);
    u16* proj    = tn;   // tn dead after QKV GEMM; proj GEMM runs later in-stream

    cvt_bf16_kernel<<<(TC * CH / 4 + 255) / 256, 256, 0, stream>>>(qkv_w, qkvw_bf, TC * CH / 4);
    cvt_bf16_kernel<<<(CH * CH / 4 + 255) / 256, 256, 0, stream>>>(out_w, outw_bf, CH * CH / 4);
    ln_kernel<<<MTOT, 256, 0, stream>>>(x, norm_w, norm_b, tn);
    gemm_bt<0><<<dim3(TC / 128, (MTOT + 127) / 128), 256, 0, stream>>>(tn, qkvw_bf, qb, kb, vb, MTOT, CH);
    vtrans_kernel<<<dim3((SPA + 63) / 64, BB * NH), 256, 0, stream>>>(vb, vtb);
    attn_kernel<<<dim3((SPA + 63) / 64, NH, BB), 256, 0, stream>>>(qb, kb, vtb, ao);
    gemm_bt<1><<<dim3(CH / 128, (MTOT + 127) / 128), 256, 0, stream>>>(ao, outw_bf, proj, nullptr, nullptr, MTOT, CH);
    final_kernel<<<(BB * CH * (SPA / 4)) / 256, 256, 0, stream>>>(proj, out_b, x, out);
}

// Round 2
// 350.908 us; speedup vs baseline: 1.1943x; 1.1943x over previous
//
#include <hip/hip_runtime.h>

typedef unsigned short u16;
typedef unsigned int u32;

#define SPA 2744        // 14*14*14 tokens
#define CH  768
#define NH  12
#define DH  64
#define BB  2
#define TC  2304        // 3*CH
#define MTOT (BB*SPA)   // 5488

typedef __bf16 bf16x8_t __attribute__((ext_vector_type(8)));
typedef __bf16 bf16x4_t __attribute__((ext_vector_type(4)));
typedef short  s16x4    __attribute__((ext_vector_type(4)));
typedef float  f32x4_t  __attribute__((ext_vector_type(4)));

static __device__ __forceinline__ u16 f2bf(float f) {
    union { float f; u32 u; } v; v.f = f;
    u32 u = v.u;
    u += 0x7fffu + ((u >> 16) & 1u);   // RNE
    return (u16)(u >> 16);
}
static __device__ __forceinline__ float bf2f(u16 h) {
    union { u32 u; float f; } v; v.u = ((u32)h) << 16;
    return v.f;
}

// ---------------- fp32 -> bf16 weight conversion ----------------
__global__ __launch_bounds__(256) void cvt_bf16_kernel(const float* __restrict__ in,
                                                       u16* __restrict__ out, int n4) {
    int i = blockIdx.x * 256 + threadIdx.x;
    if (i < n4) {
        float4 f = ((const float4*)in)[i];
        uint2 o;
        o.x = (u32)f2bf(f.x) | ((u32)f2bf(f.y) << 16);
        o.y = (u32)f2bf(f.z) | ((u32)f2bf(f.w) << 16);
        ((uint2*)out)[i] = o;
    }
}

// ---------------- LayerNorm, coalesced: block = 64 tokens ----------------
// Lanes walk tokens (contiguous n), waves walk channels. LDS transpose for
// 16B-per-token writes of tn[token][c].
__global__ __launch_bounds__(256) void ln_kernel(const float* __restrict__ x,
                                                 const float* __restrict__ w,
                                                 const float* __restrict__ bta,
                                                 u16* __restrict__ tn) {
    __shared__ float sred[4][64];
    __shared__ float qred[4][64];
    __shared__ u16 T[32][66];          // [c_local][token], stride 66 -> 2-way (free)
    int tid = threadIdx.x;
    int t = tid & 63, wvi = tid >> 6;
    int g = blockIdx.x * 64 + t;
    int gl = (g < MTOT) ? g : (MTOT - 1);
    int b = gl / SPA, n = gl - b * SPA;
    const float* base = x + (size_t)b * CH * SPA + n;

    float s = 0.f, qa = 0.f;
    for (int c = wvi; c < CH; c += 4) {
        float v = base[(size_t)c * SPA];
        s += v; qa += v * v;
    }
    sred[wvi][t] = s; qred[wvi][t] = qa;
    __syncthreads();
    s  = sred[0][t] + sred[1][t] + sred[2][t] + sred[3][t];
    qa = qred[0][t] + qred[1][t] + qred[2][t] + qred[3][t];
    float mean = s * (1.0f / CH);
    float rstd = rsqrtf(qa * (1.0f / CH) - mean * mean + 1e-5f);

    int tt = tid >> 2, cq = tid & 3;
    int g2 = blockIdx.x * 64 + tt;
    for (int cc = 0; cc < CH; cc += 32) {
        __syncthreads();
#pragma unroll
        for (int j = 0; j < 8; j++) {
            int cl = wvi + 4 * j;                  // wave-uniform channel
            int c = cc + cl;
            float v = base[(size_t)c * SPA];       // coalesced over tokens
            float nv = (v - mean) * rstd * w[c] + bta[c];
            T[cl][t] = f2bf(nv);
        }
        __syncthreads();
        if (g2 < MTOT) {
            union { u16 h[8]; int4 v4; } pk;
#pragma unroll
            for (int e = 0; e < 8; e++) pk.h[e] = T[cq * 8 + e][tt];
            *(int4*)(tn + (size_t)g2 * CH + cc + cq * 8) = pk.v4;
        }
    }
}

// ---------------- bf16 GEMM, C[m][n] = sum_k A[m][k]*Bw[n][k] ----------------
// MODE 0: scatter epilogue -> q/k/v [b][h][n][d].  MODE 1: plain bf16 [M][CH].
template<int MODE>
__global__ __launch_bounds__(256, 2) void gemm_bt(const u16* __restrict__ A,
                                                  const u16* __restrict__ Bw,
                                                  u16* __restrict__ out0,
                                                  u16* __restrict__ out1,
                                                  u16* __restrict__ out2,
                                                  int M, int K) {
    __shared__ __align__(16) u16 As[128 * 40];
    __shared__ __align__(16) u16 Bs[128 * 40];
    int tid = threadIdx.x;
    int m0 = blockIdx.y * 128;
    int n0 = blockIdx.x * 128;
    int wv = tid >> 6, lane = tid & 63;
    int wm = (wv >> 1) * 64, wn = (wv & 1) * 64;
    int quad = lane >> 4, l16 = lane & 15;

    f32x4_t zero = {0.f, 0.f, 0.f, 0.f};
    f32x4_t acc[4][4];
#pragma unroll
    for (int i = 0; i < 4; i++)
#pragma unroll
        for (int j = 0; j < 4; j++) acc[i][j] = zero;

    int arow0 = tid >> 2, acs = tid & 3;
    for (int k0 = 0; k0 < K; k0 += 32) {
        __syncthreads();
#pragma unroll
        for (int h = 0; h < 2; h++) {
            int row = arow0 + h * 64;
            int gm = m0 + row;
            int4 aval = make_int4(0, 0, 0, 0);
            if (gm < M) aval = *(const int4*)(A + (size_t)gm * K + k0 + acs * 8);
            *(int4*)(As + row * 40 + acs * 8) = aval;
            int4 bval = *(const int4*)(Bw + (size_t)(n0 + row) * K + k0 + acs * 8);
            *(int4*)(Bs + row * 40 + acs * 8) = bval;
        }
        __syncthreads();
        bf16x8_t af[4], bfr[4];
#pragma unroll
        for (int i = 0; i < 4; i++) af[i] = *(const bf16x8_t*)(As + (wm + i * 16 + l16) * 40 + quad * 8);
#pragma unroll
        for (int j = 0; j < 4; j++) bfr[j] = *(const bf16x8_t*)(Bs + (wn + j * 16 + l16) * 40 + quad * 8);
#pragma unroll
        for (int i = 0; i < 4; i++)
#pragma unroll
            for (int j = 0; j < 4; j++)
                acc[i][j] = __builtin_amdgcn_mfma_f32_16x16x32_bf16(af[i], bfr[j], acc[i][j], 0, 0, 0);
    }

    if (MODE == 0) {
        int which = n0 / CH;                  // block-uniform (CH % 128 == 0)
        int rb = n0 - which * CH;
        u16* base = (which == 0) ? out0 : ((which == 1) ? out1 : out2);
#pragma unroll
        for (int i = 0; i < 4; i++)
#pragma unroll
            for (int r = 0; r < 4; r++) {
                int gm = m0 + wm + i * 16 + quad * 4 + r;
                if (gm < M) {
                    int b = gm / SPA, n = gm - b * SPA;
#pragma unroll
                    for (int j = 0; j < 4; j++) {
                        int rem = rb + wn + j * 16 + l16;
                        int h = rem >> 6, d = rem & 63;
                        base[((size_t)(b * NH + h) * SPA + n) * DH + d] = f2bf(acc[i][j][r]);
                    }
                }
            }
    } else {
#pragma unroll
        for (int i = 0; i < 4; i++)
#pragma unroll
            for (int r = 0; r < 4; r++) {
                int gm = m0 + wm + i * 16 + quad * 4 + r;
                if (gm < M) {
#pragma unroll
                    for (int j = 0; j < 4; j++) {
                        int gn = n0 + wn + j * 16 + l16;
                        out0[(size_t)gm * CH + gn] = f2bf(acc[i][j][r]);
                    }
                }
            }
    }
}

// ---------------- V transpose: [bh][n][d] -> [bh][d][n] ----------------
__global__ __launch_bounds__(256) void vtrans_kernel(const u16* __restrict__ v,
                                                     u16* __restrict__ vt) {
    __shared__ __align__(16) u16 T[64 * 72];
    int bh = blockIdx.y;
    int n0 = blockIdx.x * 64;
    int tid = threadIdx.x;
#pragma unroll
    for (int h = 0; h < 2; h++) {
        int chunk = tid + h * 256;
        int r = chunk >> 3, cs = chunk & 7;
        int n = n0 + r;
        int4 val = make_int4(0, 0, 0, 0);
        if (n < SPA) val = *(const int4*)(v + ((size_t)bh * SPA + n) * DH + cs * 8);
        *(int4*)(T + r * 72 + cs * 8) = val;
    }
    __syncthreads();
#pragma unroll
    for (int h = 0; h < 2; h++) {
        int chunk = tid + h * 256;
        int d = chunk >> 3, cs = chunk & 7;
        int nb = n0 + cs * 8;
        if (nb < SPA) {                       // SPA % 8 == 0 -> chunk fully valid
            union { u16 s[8]; int4 v4; } tmp;
#pragma unroll
            for (int e = 0; e < 8; e++) tmp.s[e] = T[(cs * 8 + e) * 72 + d];
            *(int4*)(vt + ((size_t)bh * DH + d) * SPA + nb) = tmp.v4;
        }
    }
}

// ---------------- flash attention v2: S^T formulation ----------------
// Block = 128 q rows, 4 waves x 32 q-cols. S^T = K·Q^T via 16x16x32 (A=K rows,
// B=Q rows). C-layout of S^T (row=kv=quad*4+r, col=q=l16) IS the B-operand
// layout of mfma_f32_16x16x16bf16_1k -> P feeds PV straight from registers
// (no LDS round-trip, no scalar ds_write conflicts). O^T = V^T·P in C-layout.
__global__ __launch_bounds__(256, 2) void attn_kernel(const u16* __restrict__ q,
                                                      const u16* __restrict__ k,
                                                      const u16* __restrict__ vt,
                                                      u16* __restrict__ out) {
    __shared__ __align__(16) u16 Ks[64 * 72];   // [kv_local][d]
    __shared__ __align__(16) u16 Vs[64 * 72];   // [d][kv_local]
    int qt = blockIdx.x, h = blockIdx.y, b = blockIdx.z;
    int bh = b * NH + h;
    int tid = threadIdx.x;
    int wv = tid >> 6, lane = tid & 63;
    int quad = lane >> 4, l16 = lane & 15;
    int q0 = qt * 128;

    const u16* qg = q + (size_t)bh * SPA * DH;
    const u16* kg = k + (size_t)bh * SPA * DH;
    const u16* vg = vt + (size_t)bh * DH * SPA;

    // Q fragments (B-operand): lane holds Q[q=l16-col][d=ks*32+quad*8..+8]
    bf16x8_t bq[2][2];
    int qglob[2];
#pragma unroll
    for (int qf = 0; qf < 2; qf++) {
        int qq = q0 + wv * 32 + qf * 16 + l16;
        qglob[qf] = qq;
        int qld = (qq < SPA) ? qq : (SPA - 1);
#pragma unroll
        for (int ks = 0; ks < 2; ks++)
            bq[qf][ks] = *(const bf16x8_t*)(qg + (size_t)qld * DH + ks * 32 + quad * 8);
    }

    f32x4_t zero = {0.f, 0.f, 0.f, 0.f};
    f32x4_t o[2][4];
#pragma unroll
    for (int qf = 0; qf < 2; qf++)
#pragma unroll
        for (int i = 0; i < 4; i++) o[qf][i] = zero;
    float mrow[2] = {-1e30f, -1e30f};
    float lrow[2] = {0.f, 0.f};
    const float C = 0.18033688011112042f;      // dh^-0.5 * log2(e), scale folded into exp2

    const int nkv = (SPA + 63) / 64;           // 43
    for (int kt = 0; kt < nkv; kt++) {
        int kv0 = kt * 64;
        __syncthreads();
#pragma unroll
        for (int t2 = 0; t2 < 2; t2++) {
            int chunk = tid + t2 * 256;
            int r = chunk >> 3, cs = chunk & 7;
            int n = kv0 + r;
            int4 kval = make_int4(0, 0, 0, 0);
            if (n < SPA) kval = *(const int4*)(kg + (size_t)n * DH + cs * 8);
            *(int4*)(Ks + r * 72 + cs * 8) = kval;
            int4 vval = make_int4(0, 0, 0, 0);
            int nb = kv0 + cs * 8;
            if (nb < SPA) vval = *(const int4*)(vg + (size_t)r * SPA + nb);
            *(int4*)(Vs + r * 72 + cs * 8) = vval;
        }
        __syncthreads();

        // S^T tiles: s[qf][i] covers kv = i*16+quad*4+r (rows), q = l16 (col)
        f32x4_t s[2][4];
#pragma unroll
        for (int qf = 0; qf < 2; qf++)
#pragma unroll
            for (int i = 0; i < 4; i++) s[qf][i] = zero;
#pragma unroll
        for (int ks = 0; ks < 2; ks++) {
            bf16x8_t ak[4];
#pragma unroll
            for (int i = 0; i < 4; i++)
                ak[i] = *(const bf16x8_t*)(Ks + (i * 16 + l16) * 72 + ks * 32 + quad * 8);
#pragma unroll
            for (int i = 0; i < 4; i++) {
                s[0][i] = __builtin_amdgcn_mfma_f32_16x16x32_bf16(ak[i], bq[0][ks], s[0][i], 0, 0, 0);
                s[1][i] = __builtin_amdgcn_mfma_f32_16x16x32_bf16(ak[i], bq[1][ks], s[1][i], 0, 0, 0);
            }
        }

        if (kt == nkv - 1) {                   // mask invalid kv rows (last tile only)
#pragma unroll
            for (int i = 0; i < 4; i++)
#pragma unroll
                for (int r = 0; r < 4; r++)
                    if (kv0 + i * 16 + quad * 4 + r >= SPA) {
                        s[0][i][r] = -1e30f;
                        s[1][i][r] = -1e30f;
                    }
        }

        // online softmax per q-col (1 scalar state per lane per qf)
        s16x4 bp[2][4];
#pragma unroll
        for (int qf = 0; qf < 2; qf++) {
            float mx = s[qf][0][0];
#pragma unroll
            for (int i = 0; i < 4; i++)
#pragma unroll
                for (int r = 0; r < 4; r++) mx = fmaxf(mx, s[qf][i][r]);
            mx = fmaxf(mx, __shfl_xor(mx, 16));
            mx = fmaxf(mx, __shfl_xor(mx, 32));
            float mnew = fmaxf(mrow[qf], mx);
            float alpha = __builtin_amdgcn_exp2f((mrow[qf] - mnew) * C);
            mrow[qf] = mnew;
            float negmC = -mnew * C;
            float tsum = 0.f;
#pragma unroll
            for (int i = 0; i < 4; i++) {
                bf16x4_t pb;
#pragma unroll
                for (int r = 0; r < 4; r++) {
                    float p = __builtin_amdgcn_exp2f(fmaf(s[qf][i][r], C, negmC));
                    tsum += p;
                    pb[r] = (__bf16)p;
                }
                union { bf16x4_t b; s16x4 s; } u; u.b = pb;
                bp[qf][i] = u.s;
            }
            tsum += __shfl_xor(tsum, 16);
            tsum += __shfl_xor(tsum, 32);
            lrow[qf] = lrow[qf] * alpha + tsum;
#pragma unroll
            for (int i = 0; i < 4; i++)
#pragma unroll
                for (int r = 0; r < 4; r++) o[qf][i][r] *= alpha;
        }

        // O^T += V^T-frag · P-frag  (16x16x16, P straight from registers)
#pragma unroll
        for (int c = 0; c < 4; c++) {
#pragma unroll
            for (int i = 0; i < 4; i++) {
                s16x4 av = *(const s16x4*)(Vs + (i * 16 + l16) * 72 + c * 16 + quad * 4);
                o[0][i] = __builtin_amdgcn_mfma_f32_16x16x16bf16_1k(av, bp[0][c], o[0][i], 0, 0, 0);
                o[1][i] = __builtin_amdgcn_mfma_f32_16x16x16bf16_1k(av, bp[1][c], o[1][i], 0, 0, 0);
            }
        }
    }

    // epilogue: O^T[d = i*16+quad*4+r][q = l16-col] -> ao[token][h*64+d]
#pragma unroll
    for (int qf = 0; qf < 2; qf++) {
        int qq = qglob[qf];
        if (qq < SPA) {
            float inv = 1.0f / lrow[qf];
            u16* op = out + ((size_t)(b * SPA + qq)) * CH + h * DH;
#pragma unroll
            for (int i = 0; i < 4; i++) {
                bf16x4_t ov;
#pragma unroll
                for (int r = 0; r < 4; r++) ov[r] = (__bf16)(o[qf][i][r] * inv);
                *(bf16x4_t*)(op + i * 16 + quad * 4) = ov;
            }
        }
    }
}

// ---------------- final: transpose back + bias + residual ----------------
__global__ __launch_bounds__(256) void final_kernel(const u16* __restrict__ proj,
                                                    const float* __restrict__ ob,
                                                    const float* __restrict__ x,
                                                    float* __restrict__ out) {
    int idx = blockIdx.x * 256 + threadIdx.x;   // 0 .. BB*CH*(SPA/4)-1
    int s4 = idx % (SPA / 4);
    int t = idx / (SPA / 4);
    int c = t % CH;
    int b = t / CH;
    int n = s4 * 4;
    size_t xoff = ((size_t)(b * CH + c)) * SPA + n;
    float4 xv = *(const float4*)(x + xoff);
    const u16* pp = proj + ((size_t)(b * SPA + n)) * CH + c;
    float bias = ob[c];
    float4 r;
    r.x = xv.x + bias + bf2f(pp[0]);
    r.y = xv.y + bias + bf2f(pp[CH]);
    r.z = xv.z + bias + bf2f(pp[2 * CH]);
    r.w = xv.w + bias + bf2f(pp[3 * CH]);
    *(float4*)(out + xoff) = r;
}

extern "C" void kernel_launch(void* const* d_in, const int* in_sizes, int n_in,
                              void* d_out, int out_size, void* d_ws, size_t ws_size,
                              hipStream_t stream) {
    const float* x      = (const float*)d_in[0];
    const float* norm_w = (const float*)d_in[1];
    const float* norm_b = (const float*)d_in[2];
    const float* qkv_w  = (const float*)d_in[3];
    const float* out_w  = (const float*)d_in[4];
    const float* out_b  = (const float*)d_in[5];
    float* out = (float*)d_out;

    char* ws = (char*)d_ws;
    size_t off = 0;
    auto alloc = [&](size_t bytes) -> void* {
        void* p = ws + off;
        off += (bytes + 255) & ~(size_t)255;
        return p;
    };
    u16* tn      = (u16*)alloc((size_t)MTOT * CH * 2);
    u16* qkvw_bf = (u16*)alloc((size_t)TC * CH * 2);
    u16* outw_bf = (u16*)alloc((size_t)CH * CH * 2);
    u16* qb      = (u16*)alloc((size_t)BB * NH * SPA * DH * 2);
    u16* kb      = (u16*)alloc((size_t)BB * NH * SPA * DH * 2);
    u16* vb      = (u16*)alloc((size_t)BB * NH * SPA * DH * 2);
    u16* vtb     = (u16*)alloc((size_t)BB * NH * SPA * DH * 2);
    u16* ao      = (u16*)alloc((size_t)MTOT * CH * 2);
    u16* proj    = tn;   // tn dead after QKV GEMM; proj GEMM runs later in-stream

    cvt_bf16_kernel<<<(TC * CH / 4 + 255) / 256, 256, 0, stream>>>(qkv_w, qkvw_bf, TC * CH / 4);
    cvt_bf16_kernel<<<(CH * CH / 4 + 255) / 256, 256, 0, stream>>>(out_w, outw_bf, CH * CH / 4);
    ln_kernel<<<(MTOT + 63) / 64, 256, 0, stream>>>(x, norm_w, norm_b, tn);
    gemm_bt<0><<<dim3(TC / 128, (MTOT + 127) / 128), 256, 0, stream>>>(tn, qkvw_bf, qb, kb, vb, MTOT, CH);
    vtrans_kernel<<<dim3((SPA + 63) / 64, BB * NH), 256, 0, stream>>>(vb, vtb);
    attn_kernel<<<dim3((SPA + 127) / 128, NH, BB), 256, 0, stream>>>(qb, kb, vtb, ao);
    gemm_bt<1><<<dim3(CH / 128, (MTOT + 127) / 128), 256, 0, stream>>>(ao, outw_bf, proj, nullptr, nullptr, MTOT, CH);
    final_kernel<<<(BB * CH * (SPA / 4)) / 256, 256, 0, stream>>>(proj, out_b, x, out);
}